// Round 3
// baseline (28978.052 us; speedup 1.0000x reference)
//
#include <hip/hip_runtime.h>
#include <hip/hip_bf16.h>
#include <hip/hip_cooperative_groups.h>
#include <cstddef>

namespace cg = cooperative_groups;

// MatchLSTM round 3: cooperative persistent kernel (grid-stride, occupancy-sized,
// error-checked) with fallback to the proven round-1 multi-kernel path.
// V=50000, E=300, H=300, C=3, TP=128, TH=64, B=256
#define HDIM 300
#define EDIM 300
#define BATCH 256
#define TPREM 128
#define THYP 64
#define NTHR 256
#define KTT 32

__device__ __forceinline__ float fast_sigm(float x) {
    return 1.f / (1.f + __expf(-x));
}
__device__ __forceinline__ float fast_tanh(float x) {
    float e = __expf(2.f * x);
    return 1.f - 2.f / (e + 1.f);
}
__device__ __forceinline__ unsigned short f2bf(float f) {
    __hip_bfloat16 h = __float2bfloat16(f);
    return *reinterpret_cast<unsigned short*>(&h);
}
__device__ __forceinline__ float bf2f(unsigned short u) {
    return __uint_as_float((unsigned)u << 16);
}

// ===========================================================================
// Cooperative persistent path
// ===========================================================================
struct Params {
    const int* premise; const int* hypothesis;
    const float* w2v; const float* w_e;
    const float* W_s; const float* W_t; const float* W_m;
    const float* fc_w; const float* fc_b;
    const float* pWhh; const float* hWhh;
    const float* mWih; const float* mbih; const float* mbhh;
    const float* pWih; const float* pbih; const float* pbhh;
    const float* hWih; const float* hbih; const float* hbhh;
    float* h_s; float* h_t_all; float* wshs;
    float* c_p; float* c_h; float* h_m; float* qm; float* ab;
    unsigned short* Xp; unsigned short* Xh;   // bf16, gate-interleaved [row][hh][g]
    float* out;
};

struct SmemG { float As[KTT][34]; float Bs[KTT][68]; };
struct SmemA { float q[HDIM]; float we[HDIM]; float alpha[TPREM]; float red[4]; };
union Smem { SmemG g; SmemA a; };

// 32-row x 64-col tile of G = [A0|A1] @ [W0|W1]^T (round-1 layout, proven).
__device__ __forceinline__ void tile_mm(
    float (&acc)[2][4], Smem& sm,
    const int* tok, const float* emb,
    const float* A0, int lda0, int K0,
    const float* A1, int lda1, int K1,
    const float* W0, int ld0, const float* W1, int ld1,
    bool gated, int m0, int colbase)
{
    const int tid = threadIdx.x;
    const int K = K0 + K1;
    const int fa_b = tid >> 3;
    const int fa_k0 = (tid & 7) * 4;
    const int fb_c = tid >> 2;
    const int fb_k0 = (tid & 3) * 8;
    int wrow; bool wvalid;
    if (gated) {
        int hh = colbase + (fb_c >> 2);
        wrow = (fb_c & 3) * HDIM + hh;
        wvalid = hh < HDIM;
    } else {
        wrow = colbase + fb_c;
        wvalid = wrow < HDIM;
    }
    const int r = m0 + fa_b;
    const float* a0row = tok ? (emb + (size_t)tok[r] * EDIM)
                             : (A0 ? A0 + (size_t)r * lda0 : nullptr);
    const float* a1row = A1 ? A1 + (size_t)r * lda1 : nullptr;
    const int pb = tid & 15, hl = tid >> 4;

    for (int kc = 0; kc < K; kc += KTT) {
        #pragma unroll
        for (int u = 0; u < 4; ++u) {
            int kk = fa_k0 + u, k = kc + kk;
            float v = 0.f;
            if (k < K0)      { if (a0row) v = a0row[k]; }
            else if (k < K)  { if (a1row) v = a1row[k - K0]; }
            sm.g.As[kk][fa_b] = v;
        }
        #pragma unroll
        for (int u = 0; u < 8; ++u) {
            int kk = fb_k0 + u, k = kc + kk;
            float v = 0.f;
            if (wvalid) {
                if (k < K0)     v = W0[(size_t)wrow * ld0 + k];
                else if (k < K) v = W1[(size_t)wrow * ld1 + (k - K0)];
            }
            sm.g.Bs[kk][fb_c] = v;
        }
        __syncthreads();
        #pragma unroll
        for (int kk = 0; kk < KTT; ++kk) {
            float2 av = *(const float2*)&sm.g.As[kk][pb * 2];
            float4 wv = *(const float4*)&sm.g.Bs[kk][hl * 4];
            acc[0][0] = fmaf(av.x, wv.x, acc[0][0]);
            acc[0][1] = fmaf(av.x, wv.y, acc[0][1]);
            acc[0][2] = fmaf(av.x, wv.z, acc[0][2]);
            acc[0][3] = fmaf(av.x, wv.w, acc[0][3]);
            acc[1][0] = fmaf(av.y, wv.x, acc[1][0]);
            acc[1][1] = fmaf(av.y, wv.y, acc[1][1]);
            acc[1][2] = fmaf(av.y, wv.z, acc[1][2]);
            acc[1][3] = fmaf(av.y, wv.w, acc[1][3]);
        }
        __syncthreads();
    }
}

__device__ void attn_body(const Params& p, Smem& sm, int b) {
    const int tid = threadIdx.x;
    const int lane = tid & 63;
    const int wv = tid >> 6;
    const size_t BH = (size_t)BATCH * HDIM;

    for (int h = tid; h < HDIM; h += NTHR) {
        sm.a.q[h]  = p.qm[(size_t)b * HDIM + h];
        sm.a.we[h] = p.w_e[h];
    }
    __syncthreads();

    for (int t = wv; t < TPREM; t += 4) {
        const float* row = p.wshs + ((size_t)t * BATCH + b) * HDIM;
        float pp = 0.f;
        for (int h = lane; h < HDIM; h += 64)
            pp += sm.a.we[h] * fast_tanh(row[h] + sm.a.q[h]);
        #pragma unroll
        for (int off = 32; off; off >>= 1) pp += __shfl_xor(pp, off, 64);
        if (lane == 0) sm.a.alpha[t] = pp;
    }
    __syncthreads();

    if (wv < 2) {
        float ev = sm.a.alpha[tid];
        float m = ev;
        #pragma unroll
        for (int off = 32; off; off >>= 1) m = fmaxf(m, __shfl_xor(m, off, 64));
        if (lane == 0) sm.a.red[wv] = m;
        __syncthreads();
        float gm = fmaxf(sm.a.red[0], sm.a.red[1]);
        float e = __expf(ev - gm);
        sm.a.alpha[tid] = e;
        float s = e;
        #pragma unroll
        for (int off = 32; off; off >>= 1) s += __shfl_xor(s, off, 64);
        if (lane == 0) sm.a.red[2 + wv] = s;
        __syncthreads();
        sm.a.alpha[tid] *= 1.f / (sm.a.red[2] + sm.a.red[3]);
    } else {
        __syncthreads();
        __syncthreads();
    }
    __syncthreads();

    for (int h = tid; h < HDIM; h += NTHR) {
        const float* hsb = p.h_s + (size_t)b * HDIM + h;
        float a = 0.f;
        #pragma unroll 4
        for (int t = 0; t < TPREM; ++t)
            a = fmaf(sm.a.alpha[t], hsb[(size_t)t * BH], a);
        p.ab[(size_t)b * HDIM + h] = a;
    }
}

__global__ __launch_bounds__(NTHR, 2) void match_kernel(Params p) {
    cg::grid_group grid = cg::this_grid();
    __shared__ Smem sm;
    const int blk = blockIdx.x;
    const int nblk = gridDim.x;
    const int tid = threadIdx.x;
    const int pb = tid & 15, hl = tid >> 4;
    const size_t BH = (size_t)BATCH * HDIM;

    // ---- Phase 0: zero persistent state ----
    for (int i = blk * NTHR + tid; i < (int)BH; i += nblk * NTHR) {
        p.c_p[i] = 0.f; p.c_h[i] = 0.f; p.h_m[i] = 0.f;
    }
    grid.sync();

    // ---- Phase A: bulk x-projections -> Xp/Xh (bf16, gate-interleaved, bias folded) ----
    {
        const int PA_PREM = (TPREM * BATCH / 32) * 19;
        const int PA_TOT  = PA_PREM + (THYP * BATCH / 32) * 19;
        for (int i = blk; i < PA_TOT; i += nblk) {
            const bool isP = i < PA_PREM;
            const int idx = isP ? i : i - PA_PREM;
            const int mt = idx / 19, nt = idx % 19;
            const int m0 = mt * 32, hh0 = nt * 16;
            float acc[2][4] = {};
            tile_mm(acc, sm, isP ? p.premise : p.hypothesis, p.w2v,
                    nullptr, 0, EDIM, nullptr, 0, 0,
                    isP ? p.pWih : p.hWih, EDIM, nullptr, 0,
                    true, m0, hh0);
            const int hh = hh0 + hl;
            if (hh < HDIM) {
                const float* bi = isP ? p.pbih : p.hbih;
                const float* bh = isP ? p.pbhh : p.hbhh;
                float b0v = bi[hh] + bh[hh];
                float b1v = bi[HDIM + hh] + bh[HDIM + hh];
                float b2v = bi[2 * HDIM + hh] + bh[2 * HDIM + hh];
                float b3v = bi[3 * HDIM + hh] + bh[3 * HDIM + hh];
                unsigned short* X = isP ? p.Xp : p.Xh;
                #pragma unroll
                for (int u = 0; u < 2; ++u) {
                    int r = m0 + pb * 2 + u;
                    ushort4 s4;
                    s4.x = f2bf(acc[u][0] + b0v);
                    s4.y = f2bf(acc[u][1] + b1v);
                    s4.z = f2bf(acc[u][2] + b2v);
                    s4.w = f2bf(acc[u][3] + b3v);
                    *reinterpret_cast<ushort4*>(X + ((size_t)r * HDIM + hh) * 4) = s4;
                }
            }
        }
    }
    grid.sync();

    // ---- Phase B: recurrences (premise jobs 0..151, hyp jobs 152..303 while t<64) ----
    for (int t = 0; t < TPREM; ++t) {
        const int njobs = 152 + ((t < THYP) ? 152 : 0);
        for (int job = blk; job < njobs; job += nblk) {
            const bool isP = job < 152;
            const int idx = isP ? job : job - 152;
            const int bt = idx / 19, nt = idx % 19;
            const int b0 = bt * 32, hh0 = nt * 16;
            const float* hp = nullptr;
            if (t > 0) hp = (isP ? p.h_s : p.h_t_all) + (size_t)(t - 1) * BH;
            float acc[2][4] = {};
            if (hp)
                tile_mm(acc, sm, nullptr, nullptr, hp, HDIM, HDIM,
                        nullptr, 0, 0,
                        isP ? p.pWhh : p.hWhh, HDIM, nullptr, 0,
                        true, b0, hh0);
            const int hh = hh0 + hl;
            if (hh < HDIM) {
                const unsigned short* X = isP ? p.Xp : p.Xh;
                float* cst  = isP ? p.c_p : p.c_h;
                float* hout = (isP ? p.h_s : p.h_t_all) + (size_t)t * BH;
                #pragma unroll
                for (int u = 0; u < 2; ++u) {
                    int b = b0 + pb * 2 + u;
                    size_t rr = (size_t)t * BATCH + b;
                    ushort4 xv = *reinterpret_cast<const ushort4*>(X + (rr * HDIM + hh) * 4);
                    float gi = fast_sigm(acc[u][0] + bf2f(xv.x));
                    float gf = fast_sigm(acc[u][1] + bf2f(xv.y));
                    float gg = fast_tanh(acc[u][2] + bf2f(xv.z));
                    float go = fast_sigm(acc[u][3] + bf2f(xv.w));
                    float c = gf * cst[(size_t)b * HDIM + hh] + gi * gg;
                    cst[(size_t)b * HDIM + hh] = c;
                    hout[(size_t)b * HDIM + hh] = go * fast_tanh(c);
                }
            }
        }
        grid.sync();
    }

    // ---- Phase C: wshs = h_s @ W_s^T ----
    {
        const int NT = (TPREM * BATCH / 32) * 5;
        for (int i = blk; i < NT; i += nblk) {
            const int mt = i / 5, nt = i % 5;
            const int m0 = mt * 32, n0 = nt * 64;
            float acc[2][4] = {};
            tile_mm(acc, sm, nullptr, nullptr, p.h_s, HDIM, HDIM,
                    nullptr, 0, 0, p.W_s, HDIM, nullptr, 0,
                    false, m0, n0);
            #pragma unroll
            for (int u = 0; u < 2; ++u) {
                int r = m0 + pb * 2 + u;
                #pragma unroll
                for (int j = 0; j < 4; ++j) {
                    int col = n0 + hl * 4 + j;
                    if (col < HDIM) p.wshs[(size_t)r * HDIM + col] = acc[u][j];
                }
            }
        }
    }
    grid.sync();

    // ---- Phase D: match loop ----
    for (int k = 0; k < THYP; ++k) {
        for (int job = blk; job < 40; job += nblk) {
            const int bt = job / 5, nt = job % 5;
            const int b0 = bt * 32, n0 = nt * 64;
            float acc[2][4] = {};
            tile_mm(acc, sm, nullptr, nullptr,
                    p.h_t_all + (size_t)k * BH, HDIM, HDIM,
                    p.h_m, HDIM, HDIM,
                    p.W_t, HDIM, p.W_m, HDIM, false, b0, n0);
            #pragma unroll
            for (int u = 0; u < 2; ++u) {
                int r = b0 + pb * 2 + u;
                #pragma unroll
                for (int j = 0; j < 4; ++j) {
                    int col = n0 + hl * 4 + j;
                    if (col < HDIM) p.qm[(size_t)r * HDIM + col] = acc[u][j];
                }
            }
        }
        grid.sync();
        for (int job = blk; job < BATCH; job += nblk) attn_body(p, sm, job);
        grid.sync();
        for (int job = blk; job < 152; job += nblk) {
            const int bt = job / 19, nt = job % 19;
            const int b0 = bt * 32, hh0 = nt * 16;
            float acc[2][4] = {};
            tile_mm(acc, sm, nullptr, nullptr,
                    p.ab, HDIM, HDIM,
                    p.h_t_all + (size_t)k * BH, HDIM, HDIM,
                    p.mWih, 2 * HDIM, p.mWih + HDIM, 2 * HDIM,
                    true, b0, hh0);
            const int hh = hh0 + hl;
            if (hh < HDIM) {
                float bi0 = p.mbih[hh] + p.mbhh[hh];
                float bi2 = p.mbih[2 * HDIM + hh] + p.mbhh[2 * HDIM + hh];
                float bi3 = p.mbih[3 * HDIM + hh] + p.mbhh[3 * HDIM + hh];
                #pragma unroll
                for (int u = 0; u < 2; ++u) {
                    int b = b0 + pb * 2 + u;
                    float gi = fast_sigm(acc[u][0] + bi0);
                    float gg = fast_tanh(acc[u][2] + bi2);
                    float go = fast_sigm(acc[u][3] + bi3);
                    float c = gi * gg;
                    p.h_m[(size_t)b * HDIM + hh] = go * fast_tanh(c);
                }
            }
        }
        grid.sync();
    }

    // ---- Phase E: fc ----
    if (blk == 0) {
        int b = tid;
        float a0 = 0.f, a1 = 0.f, a2 = 0.f;
        for (int h = 0; h < HDIM; ++h) {
            float v = p.h_m[(size_t)b * HDIM + h];
            a0 = fmaf(v, p.fc_w[h], a0);
            a1 = fmaf(v, p.fc_w[HDIM + h], a1);
            a2 = fmaf(v, p.fc_w[2 * HDIM + h], a2);
        }
        p.out[b * 3 + 0] = a0 + p.fc_b[0];
        p.out[b * 3 + 1] = a1 + p.fc_b[1];
        p.out[b * 3 + 2] = a2 + p.fc_b[2];
    }
}

// ===========================================================================
// Fallback path: round-1 multi-kernel implementation (proven correct).
// ===========================================================================
__global__ void k_lstm_gates(
    const int* __restrict__ tok, const float* __restrict__ w2v,
    const float* __restrict__ A0, int K0,
    const float* __restrict__ A1, int K1,
    const float* __restrict__ W0, int ld0,
    const float* __restrict__ W1, int ld1,
    const float* __restrict__ bih, const float* __restrict__ bhh,
    const float* __restrict__ c_in, float* __restrict__ c_out,
    float* __restrict__ h_out)
{
    constexpr int KT = 32;
    __shared__ __align__(16) float As[KT][34];
    __shared__ __align__(16) float Bs[KT][68];

    const int tid = threadIdx.x;
    const int b0 = blockIdx.x * 32;
    const int hh0 = blockIdx.y * 16;
    const int K = K0 + K1;

    const int pb = tid & 15;
    const int hl = tid >> 4;
    const int fa_b = tid >> 3;
    const int fa_k0 = (tid & 7) * 4;
    const int fb_c = tid >> 2;
    const int fb_k0 = (tid & 3) * 8;
    const int fb_hh = hh0 + (fb_c >> 2);
    const int fb_g = fb_c & 3;
    const int fb_row = fb_g * HDIM + fb_hh;
    const bool fb_valid = fb_hh < HDIM;
    const int ga = b0 + fa_b;
    const int tok_b = tok ? tok[ga] : 0;

    float acc[2][4] = {{0.f,0.f,0.f,0.f},{0.f,0.f,0.f,0.f}};

    for (int k0 = 0; k0 < K; k0 += KT) {
        #pragma unroll
        for (int u = 0; u < 4; ++u) {
            int kk = fa_k0 + u;
            int k = k0 + kk;
            float v = 0.f;
            if (k < K0)      v = tok ? w2v[(size_t)tok_b * K0 + k]
                                     : A0[(size_t)ga * K0 + k];
            else if (k < K)  v = A1[(size_t)ga * K1 + (k - K0)];
            As[kk][fa_b] = v;
        }
        #pragma unroll
        for (int u = 0; u < 8; ++u) {
            int kk = fb_k0 + u;
            int k = k0 + kk;
            float v = 0.f;
            if (fb_valid) {
                if (k < K0)     v = W0[(size_t)fb_row * ld0 + k];
                else if (k < K) v = W1[(size_t)fb_row * ld1 + (k - K0)];
            }
            Bs[kk][fb_c] = v;
        }
        __syncthreads();
        #pragma unroll
        for (int kk = 0; kk < KT; ++kk) {
            float2 av = *(const float2*)&As[kk][pb * 2];
            float4 wv = *(const float4*)&Bs[kk][hl * 4];
            acc[0][0] = fmaf(av.x, wv.x, acc[0][0]);
            acc[0][1] = fmaf(av.x, wv.y, acc[0][1]);
            acc[0][2] = fmaf(av.x, wv.z, acc[0][2]);
            acc[0][3] = fmaf(av.x, wv.w, acc[0][3]);
            acc[1][0] = fmaf(av.y, wv.x, acc[1][0]);
            acc[1][1] = fmaf(av.y, wv.y, acc[1][1]);
            acc[1][2] = fmaf(av.y, wv.z, acc[1][2]);
            acc[1][3] = fmaf(av.y, wv.w, acc[1][3]);
        }
        __syncthreads();
    }

    const int hh = hh0 + hl;
    if (hh < HDIM) {
        float bi = bih[hh] + bhh[hh];
        float bf = bih[HDIM + hh] + bhh[HDIM + hh];
        float bg = bih[2 * HDIM + hh] + bhh[2 * HDIM + hh];
        float bo = bih[3 * HDIM + hh] + bhh[3 * HDIM + hh];
        #pragma unroll
        for (int u = 0; u < 2; ++u) {
            int b = b0 + pb * 2 + u;
            float gi = fast_sigm(acc[u][0] + bi);
            float gf = fast_sigm(acc[u][1] + bf);
            float gg = fast_tanh(acc[u][2] + bg);
            float go = fast_sigm(acc[u][3] + bo);
            float c = gf * c_in[(size_t)b * HDIM + hh] + gi * gg;
            c_out[(size_t)b * HDIM + hh] = c;
            h_out[(size_t)b * HDIM + hh] = go * fast_tanh(c);
        }
    }
}

template<int BM, int BN, int TM, int TN, int KT>
__global__ void k_gemm_tn(
    const float* __restrict__ A0, int K0,
    const float* __restrict__ A1, int K1,
    const float* __restrict__ B0, int ldb0,
    const float* __restrict__ B1, int ldb1,
    float* __restrict__ C, int M, int N)
{
    __shared__ __align__(16) float As[KT][BM + 4];
    __shared__ __align__(16) float Bs[KT][BN + 4];
    const int tid = threadIdx.x;
    const int m0 = blockIdx.x * BM;
    const int n0 = blockIdx.y * BN;
    const int K = K0 + K1;
    constexpr int TPM = BM / TM;
    const int tm = tid % TPM;
    const int tn = tid / TPM;

    float acc[TM][TN];
    #pragma unroll
    for (int i = 0; i < TM; ++i)
        #pragma unroll
        for (int j = 0; j < TN; ++j) acc[i][j] = 0.f;

    for (int k0 = 0; k0 < K; k0 += KT) {
        for (int i = tid; i < KT * BM; i += 256) {
            int kk = i % KT, ml = i / KT;
            int m = m0 + ml, k = k0 + kk;
            float v = 0.f;
            if (m < M) {
                if (k < K0)     v = A0[(size_t)m * K0 + k];
                else if (k < K) v = A1[(size_t)m * K1 + (k - K0)];
            }
            As[kk][ml] = v;
        }
        for (int i = tid; i < KT * BN; i += 256) {
            int kk = i % KT, nl = i / KT;
            int n = n0 + nl, k = k0 + kk;
            float v = 0.f;
            if (n < N) {
                if (k < K0)     v = B0[(size_t)n * ldb0 + k];
                else if (k < K) v = B1[(size_t)n * ldb1 + (k - K0)];
            }
            Bs[kk][nl] = v;
        }
        __syncthreads();
        #pragma unroll
        for (int kk = 0; kk < KT; ++kk) {
            float a[TM], w[TN];
            #pragma unroll
            for (int i = 0; i < TM; ++i) a[i] = As[kk][tm * TM + i];
            #pragma unroll
            for (int j = 0; j < TN; ++j) w[j] = Bs[kk][tn * TN + j];
            #pragma unroll
            for (int i = 0; i < TM; ++i)
                #pragma unroll
                for (int j = 0; j < TN; ++j)
                    acc[i][j] = fmaf(a[i], w[j], acc[i][j]);
        }
        __syncthreads();
    }
    #pragma unroll
    for (int i = 0; i < TM; ++i) {
        int m = m0 + tm * TM + i;
        if (m >= M) continue;
        #pragma unroll
        for (int j = 0; j < TN; ++j) {
            int n = n0 + tn * TN + j;
            if (n < N) C[(size_t)m * N + n] = acc[i][j];
        }
    }
}

__global__ void k_attn(const float* __restrict__ ws_hs,
                       const float* __restrict__ h_s,
                       const float* __restrict__ q,
                       const float* __restrict__ w_e,
                       float* __restrict__ a_out)
{
    const int b = blockIdx.x;
    const int tid = threadIdx.x;
    const int lane = tid & 63;
    const int wv = tid >> 6;

    __shared__ float q_s[HDIM];
    __shared__ float we_s[HDIM];
    __shared__ float alpha[TPREM];
    __shared__ float red[4];

    for (int h = tid; h < HDIM; h += 256) {
        q_s[h] = q[(size_t)b * HDIM + h];
        we_s[h] = w_e[h];
    }
    __syncthreads();

    for (int t = wv; t < TPREM; t += 4) {
        const float* row = ws_hs + ((size_t)t * BATCH + b) * HDIM;
        float p = 0.f;
        for (int h = lane; h < HDIM; h += 64)
            p += we_s[h] * fast_tanh(row[h] + q_s[h]);
        #pragma unroll
        for (int off = 32; off; off >>= 1) p += __shfl_xor(p, off, 64);
        if (lane == 0) alpha[t] = p;
    }
    __syncthreads();

    if (wv < 2) {
        float ev = alpha[tid];
        float m = ev;
        #pragma unroll
        for (int off = 32; off; off >>= 1) m = fmaxf(m, __shfl_xor(m, off, 64));
        if (lane == 0) red[wv] = m;
        __syncthreads();
        float gm = fmaxf(red[0], red[1]);
        float e = __expf(ev - gm);
        alpha[tid] = e;
        float s = e;
        #pragma unroll
        for (int off = 32; off; off >>= 1) s += __shfl_xor(s, off, 64);
        if (lane == 0) red[2 + wv] = s;
        __syncthreads();
        alpha[tid] *= 1.f / (red[2] + red[3]);
    } else {
        __syncthreads();
        __syncthreads();
    }
    __syncthreads();

    for (int h = tid; h < HDIM; h += 256) {
        const float* hsb = h_s + (size_t)b * HDIM + h;
        float acc = 0.f;
        #pragma unroll 4
        for (int t = 0; t < TPREM; ++t)
            acc = fmaf(alpha[t], hsb[(size_t)t * BATCH * HDIM], acc);
        a_out[(size_t)b * HDIM + h] = acc;
    }
}

__global__ void k_fc(const float* __restrict__ h_m,
                     const float* __restrict__ fc_w,
                     const float* __restrict__ fc_b,
                     float* __restrict__ out)
{
    const int b = threadIdx.x;
    float a0 = 0.f, a1 = 0.f, a2 = 0.f;
    for (int h = 0; h < HDIM; ++h) {
        float v = h_m[(size_t)b * HDIM + h];
        a0 = fmaf(v, fc_w[h], a0);
        a1 = fmaf(v, fc_w[HDIM + h], a1);
        a2 = fmaf(v, fc_w[2 * HDIM + h], a2);
    }
    out[b * 3 + 0] = a0 + fc_b[0];
    out[b * 3 + 1] = a1 + fc_b[1];
    out[b * 3 + 2] = a2 + fc_b[2];
}

// ===========================================================================
extern "C" void kernel_launch(void* const* d_in, const int* in_sizes, int n_in,
                              void* d_out, int out_size, void* d_ws, size_t ws_size,
                              hipStream_t stream) {
    (void)in_sizes; (void)n_in; (void)out_size;
    const int*   premise    = (const int*)d_in[0];
    const int*   hypothesis = (const int*)d_in[2];
    const float* w2v        = (const float*)d_in[4];
    const float* w_e        = (const float*)d_in[5];
    const float* W_s        = (const float*)d_in[6];
    const float* W_t        = (const float*)d_in[7];
    const float* W_m        = (const float*)d_in[8];
    const float* fc_w       = (const float*)d_in[9];
    const float* fc_b       = (const float*)d_in[10];
    const float* pWih       = (const float*)d_in[11];
    const float* pWhh       = (const float*)d_in[12];
    const float* pbih       = (const float*)d_in[13];
    const float* pbhh       = (const float*)d_in[14];
    const float* hWih       = (const float*)d_in[15];
    const float* hWhh       = (const float*)d_in[16];
    const float* hbih       = (const float*)d_in[17];
    const float* hbhh       = (const float*)d_in[18];
    const float* mWih       = (const float*)d_in[19];
    const float* mbih       = (const float*)d_in[21];
    const float* mbhh       = (const float*)d_in[22];

    const size_t BH = (size_t)BATCH * HDIM;

    // ---- try cooperative path ----
    const size_t COOP_F32  = (size_t)TPREM * BH + (size_t)THYP * BH +
                             (size_t)TPREM * BH + 5 * BH;           // 24,960,000
    const size_t COOP_BF16 = ((size_t)TPREM + THYP) * BATCH * HDIM * 4; // 58,982,400
    const size_t COOP_NEED = COOP_F32 * 4 + COOP_BF16 * 2;          // ~217.8 MB

    bool coop_done = false;
    if (ws_size >= COOP_NEED) {
        int maxb = 0;
        hipError_t oe = hipOccupancyMaxActiveBlocksPerMultiprocessor(
            &maxb, match_kernel, NTHR, 0);
        if (oe == hipSuccess && maxb >= 1) {
            int nblk = maxb * 256;           // 256 CUs on MI355X
            if (nblk > 512) nblk = 512;

            Params p;
            p.premise = premise; p.hypothesis = hypothesis;
            p.w2v = w2v; p.w_e = w_e;
            p.W_s = W_s; p.W_t = W_t; p.W_m = W_m;
            p.fc_w = fc_w; p.fc_b = fc_b;
            p.pWhh = pWhh; p.hWhh = hWhh;
            p.mWih = mWih; p.mbih = mbih; p.mbhh = mbhh;
            p.pWih = pWih; p.pbih = pbih; p.pbhh = pbhh;
            p.hWih = hWih; p.hbih = hbih; p.hbhh = hbhh;

            float* f = (float*)d_ws;
            p.h_s     = f; f += (size_t)TPREM * BH;
            p.h_t_all = f; f += (size_t)THYP * BH;
            p.wshs    = f; f += (size_t)TPREM * BH;
            p.c_p = f; f += BH;
            p.c_h = f; f += BH;
            p.h_m = f; f += BH;
            p.qm  = f; f += BH;
            p.ab  = f; f += BH;
            p.Xp = (unsigned short*)f;
            p.Xh = p.Xp + (size_t)TPREM * BATCH * HDIM * 4;
            p.out = (float*)d_out;

            void* args[] = { (void*)&p };
            hipError_t le = hipLaunchCooperativeKernel(
                (void*)match_kernel, dim3(nblk), dim3(NTHR), args, 0, stream);
            coop_done = (le == hipSuccess);
        }
    }
    if (coop_done) return;

    // ---- fallback: round-1 multi-kernel path ----
    float* ws    = (float*)d_ws;
    float* h_s   = ws;
    float* wshs  = h_s + (size_t)TPREM * BH;
    float* zeros = wshs + (size_t)TPREM * BH;
    float* c_p   = zeros + BH;
    float* c_h   = c_p + BH;
    float* c_m   = c_h + BH;
    float* ht0   = c_m + BH;
    float* ht1   = ht0 + BH;
    float* h_m   = ht1 + BH;
    float* qb    = h_m + BH;
    float* ab    = qb + BH;

    hipMemsetAsync(zeros, 0, BH * sizeof(float), stream);
    hipMemsetAsync(c_p,   0, BH * sizeof(float), stream);
    hipMemsetAsync(c_h,   0, BH * sizeof(float), stream);
    hipMemsetAsync(h_m,   0, BH * sizeof(float), stream);

    dim3 gGate(BATCH / 32, (HDIM + 15) / 16);

    for (int t = 0; t < TPREM; ++t) {
        const float* hp = t ? (h_s + (size_t)(t - 1) * BH) : zeros;
        k_lstm_gates<<<gGate, 256, 0, stream>>>(
            premise + (size_t)t * BATCH, w2v, nullptr, EDIM,
            hp, HDIM, pWih, EDIM, pWhh, HDIM,
            pbih, pbhh, c_p, c_p, h_s + (size_t)t * BH);
    }

    k_gemm_tn<64, 64, 4, 4, 16><<<dim3(TPREM * BATCH / 64, (HDIM + 63) / 64), 256, 0, stream>>>(
        h_s, HDIM, nullptr, 0, W_s, HDIM, nullptr, 0, wshs, TPREM * BATCH, HDIM);

    for (int k = 0; k < THYP; ++k) {
        const float* hp = k ? ((k & 1) ? ht0 : ht1) : zeros;
        float* hc = (k & 1) ? ht1 : ht0;
        k_lstm_gates<<<gGate, 256, 0, stream>>>(
            hypothesis + (size_t)k * BATCH, w2v, nullptr, EDIM,
            hp, HDIM, hWih, EDIM, hWhh, HDIM,
            hbih, hbhh, c_h, c_h, hc);
        k_gemm_tn<16, 64, 1, 4, 16><<<dim3(BATCH / 16, (HDIM + 63) / 64), 256, 0, stream>>>(
            hc, HDIM, h_m, HDIM, W_t, HDIM, W_m, HDIM, qb, BATCH, HDIM);
        k_attn<<<BATCH, 256, 0, stream>>>(wshs, h_s, qb, w_e, ab);
        k_lstm_gates<<<gGate, 256, 0, stream>>>(
            nullptr, nullptr, ab, HDIM,
            hc, HDIM, mWih, 2 * HDIM, mWih + HDIM, 2 * HDIM,
            mbih, mbhh, zeros, c_m, h_m);
    }

    k_fc<<<1, BATCH, 0, stream>>>(h_m, fc_w, fc_b, (float*)d_out);
}

// Round 4
// 22362.042 us; speedup vs baseline: 1.2959x; 1.2959x over previous
//
#include <hip/hip_runtime.h>
#include <hip/hip_bf16.h>
#include <hip/hip_cooperative_groups.h>
#include <cstddef>

namespace cg = cooperative_groups;

// MatchLSTM round 4: persistent cooperative kernel with per-group flag sync.
// Only 2 cg::grid.sync() total; recurrence + match loop use device-scope
// atomic counters between fixed-mapped blocks (152 prem + 152 hyp tiles,
// 8 independent b-tile groups of 19 blocks each).
// V=50000, E=300, H=300, C=3, TP=128, TH=64, B=256
#define HDIM 300
#define EDIM 300
#define BATCH 256
#define TPREM 128
#define THYP 64
#define NTHR 256
#define NBLK 304
#define KTT 32

__device__ __forceinline__ float fast_sigm(float x) {
    return 1.f / (1.f + __expf(-x));
}
__device__ __forceinline__ float fast_tanh(float x) {
    float e = __expf(2.f * x);
    return 1.f - 2.f / (e + 1.f);
}

struct Params {
    const int* premise; const int* hypothesis;
    const float* w2v; const float* w_e;
    const float* W_s; const float* W_t; const float* W_m;
    const float* fc_w; const float* fc_b;
    const float* pWih; const float* pWhh; const float* pbih; const float* pbhh;
    const float* hWih; const float* hWhh; const float* hbih; const float* hbhh;
    const float* mWih; const float* mbih; const float* mbhh;
    float* h_s;      // [TP][B][H]
    float* h_t_all;  // [TH][B][H]
    float* wshs;     // [TP][B][H]  = h_s @ W_s^T
    float* wt_ht;    // [TH][B][H]  = h_t @ W_t^T
    float* h_m;      // [B][H]
    float* ab;       // [B][H]
    unsigned* cnt;   // 32 counters, stride 32 uints
    float* out;
};

struct SmemG { float As[KTT][34]; float Bs[KTT][68]; };
struct SmemA {
    float q[304]; float we[304];
    __align__(16) float hm[304];
    float alpha[TPREM]; float red[16];
};
union Smem { SmemG g; SmemA a; };

// ---------------------------------------------------------------------------
// Flag-based sync helpers (device-scope release/acquire per guide G16/m20).
// ---------------------------------------------------------------------------
__device__ __forceinline__ void arrive(unsigned* slot) {
    __syncthreads();   // all block stores drained (vmcnt(0) before s_barrier)
    if (threadIdx.x == 0)
        __hip_atomic_fetch_add(slot, 1u, __ATOMIC_RELEASE, __HIP_MEMORY_SCOPE_AGENT);
}
__device__ __forceinline__ void wait_ge(unsigned* slot, unsigned target) {
    if (threadIdx.x == 0) {
        long guard = 0;
        while (__hip_atomic_load(slot, __ATOMIC_RELAXED, __HIP_MEMORY_SCOPE_AGENT) < target) {
            __builtin_amdgcn_s_sleep(1);
            if (++guard > (1L << 22)) break;   // deadlock insurance (~0.1 s)
        }
        (void)__hip_atomic_load(slot, __ATOMIC_ACQUIRE, __HIP_MEMORY_SCOPE_AGENT);
    }
    __syncthreads();
}

// ---------------------------------------------------------------------------
// 32-row x 64-col tile of G = [A0|A1] @ [W0|W1]^T (round-1 layout, proven).
// tok!=null: A0 row r gathers w2v[tok[r]]. gated: W row = (c&3)*HDIM + col.
// ---------------------------------------------------------------------------
__device__ __forceinline__ void tile_mm(
    float (&acc)[2][4], Smem& sm,
    const int* tok, const float* emb,
    const float* A0, int lda0, int K0,
    const float* A1, int lda1, int K1,
    const float* W0, int ld0, const float* W1, int ld1,
    bool gated, int m0, int colbase)
{
    const int tid = threadIdx.x;
    const int K = K0 + K1;
    const int fa_b = tid >> 3;
    const int fa_k0 = (tid & 7) * 4;
    const int fb_c = tid >> 2;
    const int fb_k0 = (tid & 3) * 8;
    int wrow; bool wvalid;
    if (gated) {
        int hh = colbase + (fb_c >> 2);
        wrow = (fb_c & 3) * HDIM + hh;
        wvalid = hh < HDIM;
    } else {
        wrow = colbase + fb_c;
        wvalid = wrow < HDIM;
    }
    const int r = m0 + fa_b;
    const float* a0row = tok ? (emb + (size_t)tok[r] * EDIM)
                             : (A0 ? A0 + (size_t)r * lda0 : nullptr);
    const float* a1row = A1 ? A1 + (size_t)r * lda1 : nullptr;
    const int pb = tid & 15, hl = tid >> 4;

    for (int kc = 0; kc < K; kc += KTT) {
        #pragma unroll
        for (int u = 0; u < 4; ++u) {
            int kk = fa_k0 + u, k = kc + kk;
            float v = 0.f;
            if (k < K0)      { if (a0row) v = a0row[k]; }
            else if (k < K)  { if (a1row) v = a1row[k - K0]; }
            sm.g.As[kk][fa_b] = v;
        }
        #pragma unroll
        for (int u = 0; u < 8; ++u) {
            int kk = fb_k0 + u, k = kc + kk;
            float v = 0.f;
            if (wvalid) {
                if (k < K0)     v = W0[(size_t)wrow * ld0 + k];
                else if (k < K) v = W1[(size_t)wrow * ld1 + (k - K0)];
            }
            sm.g.Bs[kk][fb_c] = v;
        }
        __syncthreads();
        #pragma unroll
        for (int kk = 0; kk < KTT; ++kk) {
            float2 av = *(const float2*)&sm.g.As[kk][pb * 2];
            float4 wv = *(const float4*)&sm.g.Bs[kk][hl * 4];
            acc[0][0] = fmaf(av.x, wv.x, acc[0][0]);
            acc[0][1] = fmaf(av.x, wv.y, acc[0][1]);
            acc[0][2] = fmaf(av.x, wv.z, acc[0][2]);
            acc[0][3] = fmaf(av.x, wv.w, acc[0][3]);
            acc[1][0] = fmaf(av.y, wv.x, acc[1][0]);
            acc[1][1] = fmaf(av.y, wv.y, acc[1][1]);
            acc[1][2] = fmaf(av.y, wv.z, acc[1][2]);
            acc[1][3] = fmaf(av.y, wv.w, acc[1][3]);
        }
        __syncthreads();
    }
}

// ---------------------------------------------------------------------------
__global__ __launch_bounds__(NTHR, 2) void match_kernel(Params p) {
    cg::grid_group grid = cg::this_grid();
    __shared__ Smem sm;
    const int blk = blockIdx.x;
    const int tid = threadIdx.x;
    const int pb = tid & 15, hl = tid >> 4;
    const size_t BH = (size_t)BATCH * HDIM;

    // ---- Phase 0: zero h_m and counters ----
    for (int i = blk * NTHR + tid; i < (int)BH; i += NBLK * NTHR) p.h_m[i] = 0.f;
    for (int i = blk * NTHR + tid; i < 32 * 32; i += NBLK * NTHR) p.cnt[i] = 0u;
    grid.sync();   // cg sync #1

    // ---- Phase B: both recurrences, per-group flag sync ----
    {
        const bool isP = blk < 152;
        const int idx = isP ? blk : blk - 152;
        const int grp = idx / 19, nt = idx % 19;
        unsigned* gslot = &p.cnt[(isP ? grp : 8 + grp) * 32];
        const int b0 = grp * 32, hh0 = nt * 16;
        const int TSTEPS = isP ? TPREM : THYP;
        const int* toks = isP ? p.premise : p.hypothesis;
        const float* Wih = isP ? p.pWih : p.hWih;
        const float* Whh = isP ? p.pWhh : p.hWhh;
        const float* bih = isP ? p.pbih : p.hbih;
        const float* bhh = isP ? p.pbhh : p.hbhh;
        float* hseq = isP ? p.h_s : p.h_t_all;
        const float* Wproj = isP ? p.W_s : p.W_t;
        float* proj = isP ? p.wshs : p.wt_ht;

        const int hh = hh0 + hl;
        float bi = 0.f, bf = 0.f, bg = 0.f, bo = 0.f;
        if (hh < HDIM) {
            bi = bih[hh] + bhh[hh];
            bf = bih[HDIM + hh] + bhh[HDIM + hh];
            bg = bih[2 * HDIM + hh] + bhh[2 * HDIM + hh];
            bo = bih[3 * HDIM + hh] + bhh[3 * HDIM + hh];
        }
        float creg[2] = {0.f, 0.f};

        for (int t = 0; t < TSTEPS; ++t) {
            if (t > 0) wait_ge(gslot, 19u * (unsigned)t);
            float acc[2][4] = {};
            tile_mm(acc, sm, toks + (size_t)t * BATCH, p.w2v,
                    nullptr, 0, EDIM,
                    (t > 0) ? hseq + (size_t)(t - 1) * BH : nullptr, HDIM, HDIM,
                    Wih, EDIM, Whh, HDIM, true, b0, hh0);
            if (hh < HDIM) {
                #pragma unroll
                for (int u = 0; u < 2; ++u) {
                    int b = b0 + pb * 2 + u;
                    float gi = fast_sigm(acc[u][0] + bi);
                    float gf = fast_sigm(acc[u][1] + bf);
                    float gg = fast_tanh(acc[u][2] + bg);
                    float go = fast_sigm(acc[u][3] + bo);
                    float c = gf * creg[u] + gi * gg;
                    creg[u] = c;
                    hseq[(size_t)t * BH + (size_t)b * HDIM + hh] = go * fast_tanh(c);
                }
            }
            arrive(gslot);
            // rotated projection job: 5 col-tiles of (W_s|W_t) @ h[t] per step,
            // spread over the 19 group blocks
            int jj = nt - (5 * t) % 19; if (jj < 0) jj += 19;
            if (jj < 5) {
                wait_ge(gslot, 19u * (unsigned)(t + 1));
                float pacc[2][4] = {};
                tile_mm(pacc, sm, nullptr, nullptr,
                        hseq + (size_t)t * BH, HDIM, HDIM,
                        nullptr, 0, 0,
                        Wproj, HDIM, nullptr, 0, false, b0, jj * 64);
                #pragma unroll
                for (int u = 0; u < 2; ++u) {
                    size_t row = (size_t)t * BATCH + b0 + pb * 2 + u;
                    #pragma unroll
                    for (int jc = 0; jc < 4; ++jc) {
                        int col = jj * 64 + hl * 4 + jc;
                        if (col < HDIM) proj[row * HDIM + col] = pacc[u][jc];
                    }
                }
            }
        }
    }
    grid.sync();   // cg sync #2

    // ---- Phase D: match loop (blocks 0..255; block = batch element) ----
    if (blk < BATCH) {
        const int b = blk, bt = blk >> 5, j = blk & 31;
        unsigned* cA = &p.cnt[(16 + bt) * 32];
        unsigned* cC = &p.cnt[(24 + bt) * 32];
        const int lane = tid & 63;
        const int wv = tid >> 6;

        for (int k = 0; k < THYP; ++k) {
            wait_ge(cC, 19u * (unsigned)k);   // h_m from prev iter ready

            // q[b] = wt_ht[k][b] + W_m @ h_m[b]   (into LDS)
            for (int h = tid; h < HDIM; h += NTHR) sm.a.hm[h] = p.h_m[(size_t)b * HDIM + h];
            __syncthreads();
            const float* wtrow = p.wt_ht + ((size_t)k * BATCH + b) * HDIM;
            for (int h = tid; h < HDIM; h += NTHR) {
                float a = wtrow[h];
                const float* wr = p.W_m + (size_t)h * HDIM;
                for (int jj = 0; jj < HDIM; jj += 4) {
                    float4 w4 = *(const float4*)&wr[jj];
                    float4 m4 = *(const float4*)&sm.a.hm[jj];
                    a = fmaf(w4.x, m4.x, fmaf(w4.y, m4.y,
                        fmaf(w4.z, m4.z, fmaf(w4.w, m4.w, a))));
                }
                sm.a.q[h] = a;
                sm.a.we[h] = p.w_e[h];
            }
            __syncthreads();

            // e[t] = w_e . tanh(wshs[t,b,:] + q); softmax; a = sum alpha*h_s
            for (int t = wv; t < TPREM; t += 4) {
                const float* row = p.wshs + ((size_t)t * BATCH + b) * HDIM;
                float pp = 0.f;
                for (int h = lane; h < HDIM; h += 64)
                    pp += sm.a.we[h] * fast_tanh(row[h] + sm.a.q[h]);
                #pragma unroll
                for (int off = 32; off; off >>= 1) pp += __shfl_xor(pp, off, 64);
                if (lane == 0) sm.a.alpha[t] = pp;
            }
            __syncthreads();
            if (wv < 2) {
                float ev = sm.a.alpha[tid];
                float m = ev;
                #pragma unroll
                for (int off = 32; off; off >>= 1) m = fmaxf(m, __shfl_xor(m, off, 64));
                if (lane == 0) sm.a.red[wv] = m;
                __syncthreads();
                float gm = fmaxf(sm.a.red[0], sm.a.red[1]);
                float e = __expf(ev - gm);
                sm.a.alpha[tid] = e;
                float s = e;
                #pragma unroll
                for (int off = 32; off; off >>= 1) s += __shfl_xor(s, off, 64);
                if (lane == 0) sm.a.red[2 + wv] = s;
                __syncthreads();
                sm.a.alpha[tid] *= 1.f / (sm.a.red[2] + sm.a.red[3]);
            } else {
                __syncthreads();
                __syncthreads();
            }
            __syncthreads();
            for (int h = tid; h < HDIM; h += NTHR) {
                const float* hsb = p.h_s + (size_t)b * HDIM + h;
                float a = 0.f;
                #pragma unroll 4
                for (int t = 0; t < TPREM; ++t)
                    a = fmaf(sm.a.alpha[t], hsb[(size_t)t * BH], a);
                p.ab[(size_t)b * HDIM + h] = a;
            }
            arrive(cA);

            // match cell tiles: 19 jobs per b-tile group
            if (j < 19) {
                wait_ge(cA, 32u * (unsigned)(k + 1));
                float acc[2][4] = {};
                tile_mm(acc, sm, nullptr, nullptr,
                        p.ab, HDIM, HDIM,
                        p.h_t_all + (size_t)k * BH, HDIM, HDIM,
                        p.mWih, 2 * HDIM, p.mWih + HDIM, 2 * HDIM,
                        true, bt * 32, j * 16);
                int hh = j * 16 + hl;
                if (hh < HDIM) {
                    float bi0 = p.mbih[hh] + p.mbhh[hh];
                    float bi2 = p.mbih[2 * HDIM + hh] + p.mbhh[2 * HDIM + hh];
                    float bi3 = p.mbih[3 * HDIM + hh] + p.mbhh[3 * HDIM + hh];
                    #pragma unroll
                    for (int u = 0; u < 2; ++u) {
                        int bb = bt * 32 + pb * 2 + u;
                        float gi = fast_sigm(acc[u][0] + bi0);
                        float gg = fast_tanh(acc[u][2] + bi2);
                        float go = fast_sigm(acc[u][3] + bi3);
                        p.h_m[(size_t)bb * HDIM + hh] = go * fast_tanh(gi * gg);
                    }
                }
                arrive(cC);
            }
        }

        // ---- FC for this b ----
        wait_ge(cC, 19u * (unsigned)THYP);
        float p0 = 0.f, p1 = 0.f, p2 = 0.f;
        for (int h = tid; h < HDIM; h += NTHR) {
            float v = p.h_m[(size_t)b * HDIM + h];
            p0 = fmaf(v, p.fc_w[h], p0);
            p1 = fmaf(v, p.fc_w[HDIM + h], p1);
            p2 = fmaf(v, p.fc_w[2 * HDIM + h], p2);
        }
        #pragma unroll
        for (int off = 32; off; off >>= 1) {
            p0 += __shfl_xor(p0, off, 64);
            p1 += __shfl_xor(p1, off, 64);
            p2 += __shfl_xor(p2, off, 64);
        }
        __syncthreads();
        if (lane == 0) {
            sm.a.red[wv * 3 + 0] = p0;
            sm.a.red[wv * 3 + 1] = p1;
            sm.a.red[wv * 3 + 2] = p2;
        }
        __syncthreads();
        if (tid == 0) {
            float o0 = 0.f, o1 = 0.f, o2 = 0.f;
            #pragma unroll
            for (int w = 0; w < 4; ++w) {
                o0 += sm.a.red[w * 3 + 0];
                o1 += sm.a.red[w * 3 + 1];
                o2 += sm.a.red[w * 3 + 2];
            }
            p.out[b * 3 + 0] = o0 + p.fc_b[0];
            p.out[b * 3 + 1] = o1 + p.fc_b[1];
            p.out[b * 3 + 2] = o2 + p.fc_b[2];
        }
    }
}

// ===========================================================================
// Fallback path: round-1 multi-kernel implementation (proven correct).
// ===========================================================================
__global__ void k_lstm_gates(
    const int* __restrict__ tok, const float* __restrict__ w2v,
    const float* __restrict__ A0, int K0,
    const float* __restrict__ A1, int K1,
    const float* __restrict__ W0, int ld0,
    const float* __restrict__ W1, int ld1,
    const float* __restrict__ bih, const float* __restrict__ bhh,
    const float* __restrict__ c_in, float* __restrict__ c_out,
    float* __restrict__ h_out)
{
    constexpr int KT = 32;
    __shared__ __align__(16) float As[KT][34];
    __shared__ __align__(16) float Bs[KT][68];

    const int tid = threadIdx.x;
    const int b0 = blockIdx.x * 32;
    const int hh0 = blockIdx.y * 16;
    const int K = K0 + K1;

    const int pb = tid & 15;
    const int hl = tid >> 4;
    const int fa_b = tid >> 3;
    const int fa_k0 = (tid & 7) * 4;
    const int fb_c = tid >> 2;
    const int fb_k0 = (tid & 3) * 8;
    const int fb_hh = hh0 + (fb_c >> 2);
    const int fb_g = fb_c & 3;
    const int fb_row = fb_g * HDIM + fb_hh;
    const bool fb_valid = fb_hh < HDIM;
    const int ga = b0 + fa_b;
    const int tok_b = tok ? tok[ga] : 0;

    float acc[2][4] = {{0.f,0.f,0.f,0.f},{0.f,0.f,0.f,0.f}};

    for (int k0 = 0; k0 < K; k0 += KT) {
        #pragma unroll
        for (int u = 0; u < 4; ++u) {
            int kk = fa_k0 + u;
            int k = k0 + kk;
            float v = 0.f;
            if (k < K0)      v = tok ? w2v[(size_t)tok_b * K0 + k]
                                     : A0[(size_t)ga * K0 + k];
            else if (k < K)  v = A1[(size_t)ga * K1 + (k - K0)];
            As[kk][fa_b] = v;
        }
        #pragma unroll
        for (int u = 0; u < 8; ++u) {
            int kk = fb_k0 + u;
            int k = k0 + kk;
            float v = 0.f;
            if (fb_valid) {
                if (k < K0)     v = W0[(size_t)fb_row * ld0 + k];
                else if (k < K) v = W1[(size_t)fb_row * ld1 + (k - K0)];
            }
            Bs[kk][fb_c] = v;
        }
        __syncthreads();
        #pragma unroll
        for (int kk = 0; kk < KT; ++kk) {
            float2 av = *(const float2*)&As[kk][pb * 2];
            float4 wv = *(const float4*)&Bs[kk][hl * 4];
            acc[0][0] = fmaf(av.x, wv.x, acc[0][0]);
            acc[0][1] = fmaf(av.x, wv.y, acc[0][1]);
            acc[0][2] = fmaf(av.x, wv.z, acc[0][2]);
            acc[0][3] = fmaf(av.x, wv.w, acc[0][3]);
            acc[1][0] = fmaf(av.y, wv.x, acc[1][0]);
            acc[1][1] = fmaf(av.y, wv.y, acc[1][1]);
            acc[1][2] = fmaf(av.y, wv.z, acc[1][2]);
            acc[1][3] = fmaf(av.y, wv.w, acc[1][3]);
        }
        __syncthreads();
    }

    const int hh = hh0 + hl;
    if (hh < HDIM) {
        float bi = bih[hh] + bhh[hh];
        float bf = bih[HDIM + hh] + bhh[HDIM + hh];
        float bg = bih[2 * HDIM + hh] + bhh[2 * HDIM + hh];
        float bo = bih[3 * HDIM + hh] + bhh[3 * HDIM + hh];
        #pragma unroll
        for (int u = 0; u < 2; ++u) {
            int b = b0 + pb * 2 + u;
            float gi = fast_sigm(acc[u][0] + bi);
            float gf = fast_sigm(acc[u][1] + bf);
            float gg = fast_tanh(acc[u][2] + bg);
            float go = fast_sigm(acc[u][3] + bo);
            float c = gf * c_in[(size_t)b * HDIM + hh] + gi * gg;
            c_out[(size_t)b * HDIM + hh] = c;
            h_out[(size_t)b * HDIM + hh] = go * fast_tanh(c);
        }
    }
}

template<int BM, int BN, int TM, int TN, int KT>
__global__ void k_gemm_tn(
    const float* __restrict__ A0, int K0,
    const float* __restrict__ A1, int K1,
    const float* __restrict__ B0, int ldb0,
    const float* __restrict__ B1, int ldb1,
    float* __restrict__ C, int M, int N)
{
    __shared__ __align__(16) float As[KT][BM + 4];
    __shared__ __align__(16) float Bs[KT][BN + 4];
    const int tid = threadIdx.x;
    const int m0 = blockIdx.x * BM;
    const int n0 = blockIdx.y * BN;
    const int K = K0 + K1;
    constexpr int TPM = BM / TM;
    const int tm = tid % TPM;
    const int tn = tid / TPM;

    float acc[TM][TN];
    #pragma unroll
    for (int i = 0; i < TM; ++i)
        #pragma unroll
        for (int j = 0; j < TN; ++j) acc[i][j] = 0.f;

    for (int k0 = 0; k0 < K; k0 += KT) {
        for (int i = tid; i < KT * BM; i += 256) {
            int kk = i % KT, ml = i / KT;
            int m = m0 + ml, k = k0 + kk;
            float v = 0.f;
            if (m < M) {
                if (k < K0)     v = A0[(size_t)m * K0 + k];
                else if (k < K) v = A1[(size_t)m * K1 + (k - K0)];
            }
            As[kk][ml] = v;
        }
        for (int i = tid; i < KT * BN; i += 256) {
            int kk = i % KT, nl = i / KT;
            int n = n0 + nl, k = k0 + kk;
            float v = 0.f;
            if (n < N) {
                if (k < K0)     v = B0[(size_t)n * ldb0 + k];
                else if (k < K) v = B1[(size_t)n * ldb1 + (k - K0)];
            }
            Bs[kk][nl] = v;
        }
        __syncthreads();
        #pragma unroll
        for (int kk = 0; kk < KT; ++kk) {
            float a[TM], w[TN];
            #pragma unroll
            for (int i = 0; i < TM; ++i) a[i] = As[kk][tm * TM + i];
            #pragma unroll
            for (int j = 0; j < TN; ++j) w[j] = Bs[kk][tn * TN + j];
            #pragma unroll
            for (int i = 0; i < TM; ++i)
                #pragma unroll
                for (int j = 0; j < TN; ++j)
                    acc[i][j] = fmaf(a[i], w[j], acc[i][j]);
        }
        __syncthreads();
    }
    #pragma unroll
    for (int i = 0; i < TM; ++i) {
        int m = m0 + tm * TM + i;
        if (m >= M) continue;
        #pragma unroll
        for (int j = 0; j < TN; ++j) {
            int n = n0 + tn * TN + j;
            if (n < N) C[(size_t)m * N + n] = acc[i][j];
        }
    }
}

__global__ void k_attn(const float* __restrict__ ws_hs,
                       const float* __restrict__ h_s,
                       const float* __restrict__ q,
                       const float* __restrict__ w_e,
                       float* __restrict__ a_out)
{
    const int b = blockIdx.x;
    const int tid = threadIdx.x;
    const int lane = tid & 63;
    const int wv = tid >> 6;

    __shared__ float q_s[HDIM];
    __shared__ float we_s[HDIM];
    __shared__ float alpha[TPREM];
    __shared__ float red[4];

    for (int h = tid; h < HDIM; h += 256) {
        q_s[h] = q[(size_t)b * HDIM + h];
        we_s[h] = w_e[h];
    }
    __syncthreads();

    for (int t = wv; t < TPREM; t += 4) {
        const float* row = ws_hs + ((size_t)t * BATCH + b) * HDIM;
        float p = 0.f;
        for (int h = lane; h < HDIM; h += 64)
            p += we_s[h] * fast_tanh(row[h] + q_s[h]);
        #pragma unroll
        for (int off = 32; off; off >>= 1) p += __shfl_xor(p, off, 64);
        if (lane == 0) alpha[t] = p;
    }
    __syncthreads();

    if (wv < 2) {
        float ev = alpha[tid];
        float m = ev;
        #pragma unroll
        for (int off = 32; off; off >>= 1) m = fmaxf(m, __shfl_xor(m, off, 64));
        if (lane == 0) red[wv] = m;
        __syncthreads();
        float gm = fmaxf(red[0], red[1]);
        float e = __expf(ev - gm);
        alpha[tid] = e;
        float s = e;
        #pragma unroll
        for (int off = 32; off; off >>= 1) s += __shfl_xor(s, off, 64);
        if (lane == 0) red[2 + wv] = s;
        __syncthreads();
        alpha[tid] *= 1.f / (red[2] + red[3]);
    } else {
        __syncthreads();
        __syncthreads();
    }
    __syncthreads();

    for (int h = tid; h < HDIM; h += 256) {
        const float* hsb = h_s + (size_t)b * HDIM + h;
        float acc = 0.f;
        #pragma unroll 4
        for (int t = 0; t < TPREM; ++t)
            acc = fmaf(alpha[t], hsb[(size_t)t * BATCH * HDIM], acc);
        a_out[(size_t)b * HDIM + h] = acc;
    }
}

__global__ void k_fc(const float* __restrict__ h_m,
                     const float* __restrict__ fc_w,
                     const float* __restrict__ fc_b,
                     float* __restrict__ out)
{
    const int b = threadIdx.x;
    float a0 = 0.f, a1 = 0.f, a2 = 0.f;
    for (int h = 0; h < HDIM; ++h) {
        float v = h_m[(size_t)b * HDIM + h];
        a0 = fmaf(v, fc_w[h], a0);
        a1 = fmaf(v, fc_w[HDIM + h], a1);
        a2 = fmaf(v, fc_w[2 * HDIM + h], a2);
    }
    out[b * 3 + 0] = a0 + fc_b[0];
    out[b * 3 + 1] = a1 + fc_b[1];
    out[b * 3 + 2] = a2 + fc_b[2];
}

// ===========================================================================
extern "C" void kernel_launch(void* const* d_in, const int* in_sizes, int n_in,
                              void* d_out, int out_size, void* d_ws, size_t ws_size,
                              hipStream_t stream) {
    (void)in_sizes; (void)n_in; (void)out_size;
    const int*   premise    = (const int*)d_in[0];
    const int*   hypothesis = (const int*)d_in[2];
    const float* w2v        = (const float*)d_in[4];
    const float* w_e        = (const float*)d_in[5];
    const float* W_s        = (const float*)d_in[6];
    const float* W_t        = (const float*)d_in[7];
    const float* W_m        = (const float*)d_in[8];
    const float* fc_w       = (const float*)d_in[9];
    const float* fc_b       = (const float*)d_in[10];
    const float* pWih       = (const float*)d_in[11];
    const float* pWhh       = (const float*)d_in[12];
    const float* pbih       = (const float*)d_in[13];
    const float* pbhh       = (const float*)d_in[14];
    const float* hWih       = (const float*)d_in[15];
    const float* hWhh       = (const float*)d_in[16];
    const float* hbih       = (const float*)d_in[17];
    const float* hbhh       = (const float*)d_in[18];
    const float* mWih       = (const float*)d_in[19];
    const float* mbih       = (const float*)d_in[21];
    const float* mbhh       = (const float*)d_in[22];

    const size_t BH = (size_t)BATCH * HDIM;

    // cooperative path workspace: counters (4 KB) + 386*BH floats (~118.6 MB)
    const size_t COOP_NEED = 4096 + (386 * BH) * sizeof(float);

    bool coop_done = false;
    if (ws_size >= COOP_NEED) {
        int maxb = 0;
        hipError_t oe = hipOccupancyMaxActiveBlocksPerMultiprocessor(
            &maxb, match_kernel, NTHR, 0);
        if (oe == hipSuccess && maxb * 256 >= NBLK) {
            Params p;
            p.premise = premise; p.hypothesis = hypothesis;
            p.w2v = w2v; p.w_e = w_e;
            p.W_s = W_s; p.W_t = W_t; p.W_m = W_m;
            p.fc_w = fc_w; p.fc_b = fc_b;
            p.pWih = pWih; p.pWhh = pWhh; p.pbih = pbih; p.pbhh = pbhh;
            p.hWih = hWih; p.hWhh = hWhh; p.hbih = hbih; p.hbhh = hbhh;
            p.mWih = mWih; p.mbih = mbih; p.mbhh = mbhh;

            p.cnt = (unsigned*)d_ws;
            float* f = (float*)((char*)d_ws + 4096);
            p.h_s     = f; f += (size_t)TPREM * BH;
            p.h_t_all = f; f += (size_t)THYP * BH;
            p.wshs    = f; f += (size_t)TPREM * BH;
            p.wt_ht   = f; f += (size_t)THYP * BH;
            p.h_m     = f; f += BH;
            p.ab      = f; f += BH;
            p.out = (float*)d_out;

            void* args[] = { (void*)&p };
            hipError_t le = hipLaunchCooperativeKernel(
                (void*)match_kernel, dim3(NBLK), dim3(NTHR), args, 0, stream);
            coop_done = (le == hipSuccess);
        }
    }
    if (coop_done) return;

    // ---- fallback: round-1 multi-kernel path ----
    float* ws    = (float*)d_ws;
    float* h_s   = ws;
    float* wshs  = h_s + (size_t)TPREM * BH;
    float* zeros = wshs + (size_t)TPREM * BH;
    float* c_p   = zeros + BH;
    float* c_h   = c_p + BH;
    float* c_m   = c_h + BH;
    float* ht0   = c_m + BH;
    float* ht1   = ht0 + BH;
    float* h_m   = ht1 + BH;
    float* qb    = h_m + BH;
    float* ab    = qb + BH;

    hipMemsetAsync(zeros, 0, BH * sizeof(float), stream);
    hipMemsetAsync(c_p,   0, BH * sizeof(float), stream);
    hipMemsetAsync(c_h,   0, BH * sizeof(float), stream);
    hipMemsetAsync(h_m,   0, BH * sizeof(float), stream);

    dim3 gGate(BATCH / 32, (HDIM + 15) / 16);

    for (int t = 0; t < TPREM; ++t) {
        const float* hp = t ? (h_s + (size_t)(t - 1) * BH) : zeros;
        k_lstm_gates<<<gGate, 256, 0, stream>>>(
            premise + (size_t)t * BATCH, w2v, nullptr, EDIM,
            hp, HDIM, pWih, EDIM, pWhh, HDIM,
            pbih, pbhh, c_p, c_p, h_s + (size_t)t * BH);
    }

    k_gemm_tn<64, 64, 4, 4, 16><<<dim3(TPREM * BATCH / 64, (HDIM + 63) / 64), 256, 0, stream>>>(
        h_s, HDIM, nullptr, 0, W_s, HDIM, nullptr, 0, wshs, TPREM * BATCH, HDIM);

    for (int k = 0; k < THYP; ++k) {
        const float* hp = k ? ((k & 1) ? ht0 : ht1) : zeros;
        float* hc = (k & 1) ? ht1 : ht0;
        k_lstm_gates<<<gGate, 256, 0, stream>>>(
            hypothesis + (size_t)k * BATCH, w2v, nullptr, EDIM,
            hp, HDIM, hWih, EDIM, hWhh, HDIM,
            hbih, hbhh, c_h, c_h, hc);
        k_gemm_tn<16, 64, 1, 4, 16><<<dim3(BATCH / 16, (HDIM + 63) / 64), 256, 0, stream>>>(
            hc, HDIM, h_m, HDIM, W_t, HDIM, W_m, HDIM, qb, BATCH, HDIM);
        k_attn<<<BATCH, 256, 0, stream>>>(wshs, h_s, qb, w_e, ab);
        k_lstm_gates<<<gGate, 256, 0, stream>>>(
            nullptr, nullptr, ab, HDIM,
            hc, HDIM, mWih, 2 * HDIM, mWih + HDIM, 2 * HDIM,
            mbih, mbhh, zeros, c_m, h_m);
    }

    k_fc<<<1, BATCH, 0, stream>>>(h_m, fc_w, fc_b, (float*)d_out);
}